// Round 8
// baseline (3863.541 us; speedup 1.0000x reference)
//
#include <hip/hip_runtime.h>

#define HIDDEN 4096
#define INTER 14336
#define NTOK 8192   // B*S = 4*2048

typedef _Float16 half8 __attribute__((ext_vector_type(8)));
typedef float floatx4 __attribute__((ext_vector_type(4)));

#define AS1C(p) ((const __attribute__((address_space(1))) void*)(p))
#define AS3(p)  ((__attribute__((address_space(3))) void*)(p))
#define SBAR()  __builtin_amdgcn_s_barrier()
#define WAIT_VM(N) asm volatile("s_waitcnt vmcnt(" #N ")" ::: "memory")
#define PRIO(x) __builtin_amdgcn_s_setprio(x)
#define MFMA16(A,B,C) __builtin_amdgcn_mfma_f32_16x16x32_f16(A,B,C,0,0,0)

// ---------------- conversion kernels ----------------

__global__ void cvt_w_kernel(const int* __restrict__ src, _Float16* __restrict__ dst, long n) {
    long i0 = ((long)blockIdx.x * blockDim.x + threadIdx.x) * 8;
    long stride = (long)gridDim.x * blockDim.x * 8;
    for (long i = i0; i < n; i += stride) {
        int4 a = *(const int4*)(src + i);
        int4 b = *(const int4*)(src + i + 4);
        half8 h;
        h[0] = (_Float16)a.x; h[1] = (_Float16)a.y; h[2] = (_Float16)a.z; h[3] = (_Float16)a.w;
        h[4] = (_Float16)b.x; h[5] = (_Float16)b.y; h[6] = (_Float16)b.z; h[7] = (_Float16)b.w;
        *(half8*)(dst + i) = h;
    }
}

__global__ void cvt_x_kernel(const float* __restrict__ src, _Float16* __restrict__ dst, long n) {
    long i0 = ((long)blockIdx.x * blockDim.x + threadIdx.x) * 8;
    long stride = (long)gridDim.x * blockDim.x * 8;
    for (long i = i0; i < n; i += stride) {
        float4 a = *(const float4*)(src + i);
        float4 b = *(const float4*)(src + i + 4);
        half8 h;
        h[0] = (_Float16)a.x; h[1] = (_Float16)a.y; h[2] = (_Float16)a.z; h[3] = (_Float16)a.w;
        h[4] = (_Float16)b.x; h[5] = (_Float16)b.y; h[6] = (_Float16)b.z; h[7] = (_Float16)b.w;
        *(half8*)(dst + i) = h;
    }
}

// ---------------- fused gate+up (R4 4-phase + T4 counted vmcnt) ----------------
// BM=256, BN=128, BK=64, 512 thr (8 waves 2Mx4N). LDS 128KB: 2buf x (A32K+G16K+U16K).
// Staging of t+1 (dead buffer), grouped by consuming phase:
//   batch1 @P0: A rows{0-63,128-191} (aLo rows) + G   -> read at P0 of t+1
//   batch2 @P1: A rows{64-127,192-255} (aHi rows) + U -> read at P1/P2 of t+1
// Counted waits (release exactly one 4-load batch, staged 4 phases earlier):
//   P1-start: vmcnt(4)  [release batch2(t); batch1(t+1) stays in flight]
//   P3-end:   vmcnt(4)  [release batch1(t+1); batch2(t+1) stays in flight]
// Tails fall back to vmcnt(0). No drain in steady state.

__global__ __launch_bounds__(512, 2) void gateup_kernel(
        const _Float16* __restrict__ Aptr, const _Float16* __restrict__ Bgp,
        const _Float16* __restrict__ Bup, const float* __restrict__ gsc,
        const float* __restrict__ usc, _Float16* __restrict__ H)
{
    constexpr int KDIM = HIDDEN;
    constexpr int NT = KDIM / 64;      // 64
    constexpr int NBN = INTER / 128;   // 112
    __shared__ _Float16 sA[2][256 * 64];
    __shared__ _Float16 sG[2][128 * 64];
    __shared__ _Float16 sU[2][128 * 64];

    const int tid  = threadIdx.x;
    const int lane = tid & 63;
    const int wid  = tid >> 6;
    const int wr   = wid >> 2;   // 0..1
    const int wc   = wid & 3;    // 0..3

    const int nwg = gridDim.x;
    const int bid = blockIdx.x;
    const int swz = (bid & 7) * (nwg >> 3) + (bid >> 3);
    const int bm = swz / NBN;
    const int bn = swz % NBN;

    const int srow  = tid >> 3;                  // 0..63
    const int sslot = (tid & 7) ^ (srow & 7);    // T2 pre-swizzled source slot
    const _Float16* gA = Aptr + ((long)bm * 256 + srow) * KDIM + sslot * 8;
    const _Float16* gG = Bgp + ((long)bn * 128 + srow) * KDIM + sslot * 8;
    const _Float16* gU = Bup + ((long)bn * 128 + srow) * KDIM + sslot * 8;

    auto stageB1 = [&](int t) {   // A passes 0,2 (aLo rows) + G : 4 loads
        const int b = t & 1;
        _Float16* dA = &sA[b][tid * 8];
        _Float16* dG = &sG[b][tid * 8];
        const _Float16* sa = gA + (long)t * 64;
        const _Float16* sg = gG + (long)t * 64;
        __builtin_amdgcn_global_load_lds(AS1C(sa),                    AS3(dA),            16, 0, 0);
        __builtin_amdgcn_global_load_lds(AS1C(sa + 2l * 64 * KDIM),   AS3(dA + 2 * 4096), 16, 0, 0);
        __builtin_amdgcn_global_load_lds(AS1C(sg),                    AS3(dG),            16, 0, 0);
        __builtin_amdgcn_global_load_lds(AS1C(sg + 1l * 64 * KDIM),   AS3(dG + 4096),     16, 0, 0);
    };
    auto stageB2 = [&](int t) {   // A passes 1,3 (aHi rows) + U : 4 loads
        const int b = t & 1;
        _Float16* dA = &sA[b][tid * 8];
        _Float16* dU = &sU[b][tid * 8];
        const _Float16* sa = gA + (long)t * 64;
        const _Float16* su = gU + (long)t * 64;
        __builtin_amdgcn_global_load_lds(AS1C(sa + 1l * 64 * KDIM),   AS3(dA + 1 * 4096), 16, 0, 0);
        __builtin_amdgcn_global_load_lds(AS1C(sa + 3l * 64 * KDIM),   AS3(dA + 3 * 4096), 16, 0, 0);
        __builtin_amdgcn_global_load_lds(AS1C(su),                    AS3(dU),            16, 0, 0);
        __builtin_amdgcn_global_load_lds(AS1C(su + 1l * 64 * KDIM),   AS3(dU + 4096),     16, 0, 0);
    };

    const int arow = wr * 128 + (lane & 15);
    const int brow = wc * 32  + (lane & 15);
    const int sl0 = ((lane >> 4) ^ (lane & 7)) * 8;
    const int sl1 = ((4 + (lane >> 4)) ^ (lane & 7)) * 8;
    const int aof0 = arow * 64 + sl0, aof1 = arow * 64 + sl1;
    const int bof0 = brow * 64 + sl0, bof1 = brow * 64 + sl1;

    floatx4 ag[8][2] = {};
    floatx4 au[8][2] = {};
    half8 a[8][2], bg[2][2], bu[2][2];

    // prologue: tile 0 fully staged and landed
    stageB1(0);
    stageB2(0);
    WAIT_VM(0);
    SBAR();

    for (int t = 0; t < NT; ++t) {
        const _Float16* A = &sA[t & 1][0];
        const _Float16* G = &sG[t & 1][0];
        const _Float16* U = &sU[t & 1][0];
        const bool st = (t + 1 < NT);

        // ---- P0: stage batch1(t+1); ds aLo + bg; MFMA g m0-3 ----
        if (st) stageB1(t + 1);
#pragma unroll
        for (int m = 0; m < 4; ++m) {
            a[m][0] = *(const half8*)(A + aof0 + m * 1024);
            a[m][1] = *(const half8*)(A + aof1 + m * 1024);
        }
#pragma unroll
        for (int n = 0; n < 2; ++n) {
            bg[n][0] = *(const half8*)(G + bof0 + n * 1024);
            bg[n][1] = *(const half8*)(G + bof1 + n * 1024);
        }
        SBAR();
        PRIO(1);
#pragma unroll
        for (int m = 0; m < 4; ++m)
#pragma unroll
            for (int n = 0; n < 2; ++n) {
                ag[m][n] = MFMA16(a[m][0], bg[n][0], ag[m][n]);
                ag[m][n] = MFMA16(a[m][1], bg[n][1], ag[m][n]);
            }
        PRIO(0);
        SBAR();

        // ---- P1: release batch2(t); stage batch2(t+1); ds aHi; MFMA g m4-7 ----
        if (t + 1 < NT) { WAIT_VM(4); } else { WAIT_VM(0); }
        if (st) stageB2(t + 1);
#pragma unroll
        for (int m = 4; m < 8; ++m) {
            a[m][0] = *(const half8*)(A + aof0 + m * 1024);
            a[m][1] = *(const half8*)(A + aof1 + m * 1024);
        }
        SBAR();
        PRIO(1);
#pragma unroll
        for (int m = 4; m < 8; ++m)
#pragma unroll
            for (int n = 0; n < 2; ++n) {
                ag[m][n] = MFMA16(a[m][0], bg[n][0], ag[m][n]);
                ag[m][n] = MFMA16(a[m][1], bg[n][1], ag[m][n]);
            }
        PRIO(0);
        SBAR();

        // ---- P2: ds bu; MFMA u m0-3 ----
#pragma unroll
        for (int n = 0; n < 2; ++n) {
            bu[n][0] = *(const half8*)(U + bof0 + n * 1024);
            bu[n][1] = *(const half8*)(U + bof1 + n * 1024);
        }
        SBAR();
        PRIO(1);
#pragma unroll
        for (int m = 0; m < 4; ++m)
#pragma unroll
            for (int n = 0; n < 2; ++n) {
                au[m][n] = MFMA16(a[m][0], bu[n][0], au[m][n]);
                au[m][n] = MFMA16(a[m][1], bu[n][1], au[m][n]);
            }
        PRIO(0);
        SBAR();

        // ---- P3: MFMA u m4-7; release batch1(t+1) ----
        PRIO(1);
#pragma unroll
        for (int m = 4; m < 8; ++m)
#pragma unroll
            for (int n = 0; n < 2; ++n) {
                au[m][n] = MFMA16(a[m][0], bu[n][0], au[m][n]);
                au[m][n] = MFMA16(a[m][1], bu[n][1], au[m][n]);
            }
        PRIO(0);
        if (st) { WAIT_VM(4); } else { WAIT_VM(0); }
        SBAR();
    }

    // ---- epilogue: h = silu(g*gs) * (u*us), fp16 ----
    const int orow = bm * 256 + wr * 128 + ((lane >> 4) * 4);
    const int ocol = bn * 128 + wc * 32 + (lane & 15);
#pragma unroll
    for (int n = 0; n < 2; ++n) {
        const int col = ocol + n * 16;
        const float gs = gsc[col];
        const float us = usc[col];
#pragma unroll
        for (int m = 0; m < 8; ++m) {
            const int row = orow + m * 16;
#pragma unroll
            for (int q = 0; q < 4; ++q) {
                const float g = ag[m][n][q] * gs;
                const float u = au[m][n][q] * us;
                H[(long)(row + q) * INTER + col] = (_Float16)(g / (1.0f + __expf(-g)) * u);
            }
        }
    }
}

// ---------------- down GEMM (R4 4-phase 256x256 + T4 counted vmcnt) ----------------
// Staging of t+1: batch1 @P0 = B passes 0-3 (all B rows read at P0/P1);
//                 batch2 @P1 = A passes ordered {0,2,1,3} (aLo rows first).
// Waits: P2-start vmcnt(8) [release A p1,p3(t)]; P3-end vmcnt(2)
//        [release B(t+1) + A p0,p2(t+1)]. Tails -> vmcnt(0).

__global__ __launch_bounds__(512, 2) void down_kernel(
        const _Float16* __restrict__ Aptr, const _Float16* __restrict__ Bptr,
        const float* __restrict__ dsc, float* __restrict__ out)
{
    constexpr int KDIM = INTER;
    constexpr int NT = KDIM / 64;     // 224
    constexpr int NBN = HIDDEN / 256; // 16
    __shared__ _Float16 sA[2][256 * 64];
    __shared__ _Float16 sB[2][256 * 64];

    const int tid  = threadIdx.x;
    const int lane = tid & 63;
    const int wid  = tid >> 6;
    const int wr   = wid >> 2;
    const int wc   = wid & 3;

    const int nwg = gridDim.x;
    const int bid = blockIdx.x;
    const int swz = (bid & 7) * (nwg >> 3) + (bid >> 3);
    const int bm = swz / NBN;
    const int bn = swz % NBN;

    const int srow  = tid >> 3;
    const int sslot = (tid & 7) ^ (srow & 7);
    const _Float16* gA = Aptr + ((long)bm * 256 + srow) * KDIM + sslot * 8;
    const _Float16* gB = Bptr + ((long)bn * 256 + srow) * KDIM + sslot * 8;

    auto stageB1 = [&](int t) {   // B passes 0..3 : 4 loads
        const int b = t & 1;
        _Float16* dB = &sB[b][tid * 8];
        const _Float16* sb = gB + (long)t * 64;
#pragma unroll
        for (int p = 0; p < 4; ++p)
            __builtin_amdgcn_global_load_lds(AS1C(sb + (long)p * 64 * KDIM), AS3(dB + p * 4096), 16, 0, 0);
    };
    auto stageB2 = [&](int t) {   // A passes {0,2,1,3} : 4 loads (aLo rows oldest)
        const int b = t & 1;
        _Float16* dA = &sA[b][tid * 8];
        const _Float16* sa = gA + (long)t * 64;
        __builtin_amdgcn_global_load_lds(AS1C(sa),                  AS3(dA),            16, 0, 0);
        __builtin_amdgcn_global_load_lds(AS1C(sa + 2l * 64 * KDIM), AS3(dA + 2 * 4096), 16, 0, 0);
        __builtin_amdgcn_global_load_lds(AS1C(sa + 1l * 64 * KDIM), AS3(dA + 1 * 4096), 16, 0, 0);
        __builtin_amdgcn_global_load_lds(AS1C(sa + 3l * 64 * KDIM), AS3(dA + 3 * 4096), 16, 0, 0);
    };

    const int arow = wr * 128 + (lane & 15);
    const int brow = wc * 64  + (lane & 15);
    const int sl0 = ((lane >> 4) ^ (lane & 7)) * 8;
    const int sl1 = ((4 + (lane >> 4)) ^ (lane & 7)) * 8;
    const int aof0 = arow * 64 + sl0, aof1 = arow * 64 + sl1;
    const int bof0 = brow * 64 + sl0, bof1 = brow * 64 + sl1;

    floatx4 acc[8][4] = {};
    half8 a[8][2], b[4][2];

    stageB1(0);
    stageB2(0);
    WAIT_VM(0);
    SBAR();

    for (int t = 0; t < NT; ++t) {
        const _Float16* A = &sA[t & 1][0];
        const _Float16* B = &sB[t & 1][0];
        const bool st = (t + 1 < NT);

        // ---- P0: stage batch1(t+1)=B; ds aLo + b01; MFMA m0-3 x n0-1 ----
        if (st) stageB1(t + 1);
#pragma unroll
        for (int m = 0; m < 4; ++m) {
            a[m][0] = *(const half8*)(A + aof0 + m * 1024);
            a[m][1] = *(const half8*)(A + aof1 + m * 1024);
        }
#pragma unroll
        for (int n = 0; n < 2; ++n) {
            b[n][0] = *(const half8*)(B + bof0 + n * 1024);
            b[n][1] = *(const half8*)(B + bof1 + n * 1024);
        }
        SBAR();
        PRIO(1);
#pragma unroll
        for (int m = 0; m < 4; ++m)
#pragma unroll
            for (int n = 0; n < 2; ++n) {
                acc[m][n] = MFMA16(a[m][0], b[n][0], acc[m][n]);
                acc[m][n] = MFMA16(a[m][1], b[n][1], acc[m][n]);
            }
        PRIO(0);
        SBAR();

        // ---- P1: stage batch2(t+1)=A; ds b23; MFMA m0-3 x n2-3 ----
        if (st) stageB2(t + 1);
#pragma unroll
        for (int n = 2; n < 4; ++n) {
            b[n][0] = *(const half8*)(B + bof0 + n * 1024);
            b[n][1] = *(const half8*)(B + bof1 + n * 1024);
        }
        SBAR();
        PRIO(1);
#pragma unroll
        for (int m = 0; m < 4; ++m)
#pragma unroll
            for (int n = 2; n < 4; ++n) {
                acc[m][n] = MFMA16(a[m][0], b[n][0], acc[m][n]);
                acc[m][n] = MFMA16(a[m][1], b[n][1], acc[m][n]);
            }
        PRIO(0);
        SBAR();

        // ---- P2: release A p1,p3(t); ds aHi; MFMA m4-7 x n2-3 ----
        if (t + 1 < NT) { WAIT_VM(8); } else { WAIT_VM(0); }
#pragma unroll
        for (int m = 4; m < 8; ++m) {
            a[m][0] = *(const half8*)(A + aof0 + m * 1024);
            a[m][1] = *(const half8*)(A + aof1 + m * 1024);
        }
        SBAR();
        PRIO(1);
#pragma unroll
        for (int m = 4; m < 8; ++m)
#pragma unroll
            for (int n = 2; n < 4; ++n) {
                acc[m][n] = MFMA16(a[m][0], b[n][0], acc[m][n]);
                acc[m][n] = MFMA16(a[m][1], b[n][1], acc[m][n]);
            }
        PRIO(0);
        SBAR();

        // ---- P3: MFMA m4-7 x n0-1; release B(t+1)+A p0,p2(t+1) ----
        PRIO(1);
#pragma unroll
        for (int m = 4; m < 8; ++m)
#pragma unroll
            for (int n = 0; n < 2; ++n) {
                acc[m][n] = MFMA16(a[m][0], b[n][0], acc[m][n]);
                acc[m][n] = MFMA16(a[m][1], b[n][1], acc[m][n]);
            }
        PRIO(0);
        if (st) { WAIT_VM(2); } else { WAIT_VM(0); }
        SBAR();
    }

    const int orow = bm * 256 + wr * 128 + ((lane >> 4) * 4);
    const int ocol = bn * 256 + wc * 64 + (lane & 15);
#pragma unroll
    for (int n = 0; n < 4; ++n) {
        const int col = ocol + n * 16;
        const float sc = dsc[col];
#pragma unroll
        for (int m = 0; m < 8; ++m) {
            const int row = orow + m * 16;
#pragma unroll
            for (int q = 0; q < 4; ++q)
                out[(long)(row + q) * HIDDEN + col] = acc[m][n][q] * sc;
        }
    }
}

// ---------------- launch ----------------

extern "C" void kernel_launch(void* const* d_in, const int* in_sizes, int n_in,
                              void* d_out, int out_size, void* d_ws, size_t ws_size,
                              hipStream_t stream) {
    const float* x   = (const float*)d_in[0];
    const int*   gw  = (const int*)d_in[1];
    const float* gsc = (const float*)d_in[2];
    const int*   uw  = (const int*)d_in[3];
    const float* usc = (const float*)d_in[4];
    const int*   dw  = (const int*)d_in[5];
    const float* dsc = (const float*)d_in[6];
    float* out = (float*)d_out;

    char* ws = (char*)d_ws;
    _Float16* x16  = (_Float16*)(ws);                    //  64 MiB
    _Float16* wg16 = (_Float16*)(ws + 67108864ll);       // 112 MiB
    _Float16* wu16 = (_Float16*)(ws + 184549376ll);      // 112 MiB
    _Float16* wd16 = (_Float16*)(ws + 301989888ll);      // 112 MiB
    _Float16* h16  = (_Float16*)(ws + 419430400ll);      // 224 MiB

    cvt_x_kernel<<<4096, 256, 0, stream>>>(x,  x16,  (long)NTOK * HIDDEN);
    cvt_w_kernel<<<4096, 256, 0, stream>>>(gw, wg16, (long)INTER * HIDDEN);
    cvt_w_kernel<<<4096, 256, 0, stream>>>(uw, wu16, (long)INTER * HIDDEN);
    cvt_w_kernel<<<4096, 256, 0, stream>>>(dw, wd16, (long)HIDDEN * INTER);

    // fused gate+up+SwiGLU: [8192 x 14336], h fp16
    gateup_kernel<<<(NTOK / 256) * (INTER / 128), 512, 0, stream>>>(
        x16, wg16, wu16, gsc, usc, h16);
    // down: [8192 x 4096] = H * Wd^T, fp32 out
    down_kernel<<<(NTOK / 256) * (HIDDEN / 256), 512, 0, stream>>>(
        h16, wd16, dsc, out);
}